// Round 3
// baseline (3311.140 us; speedup 1.0000x reference)
//
#include <hip/hip_runtime.h>
#include <hip/hip_bf16.h>
#include <math.h>

// ModelParallelSoftmaxLoss: loss = mean(logsumexp(x@W^T + b) - (x@W^T+b)[lb])
// N=4096, D=512, V=100000.
// R3: MX-fp8 (e4m3, K=128 mfma_scale) GEMM + max-free sum-exp. tgt logit exact fp32.
//     W quantized as W*32 with MX scale 2^-5 (avoids e4m3 subnormal range).

#define N_ROWS 4096
#define DIM    512              // elements per row == bytes per row in fp8
#define VOCAB  100000
#define NTILES 782              // ceil(100000/128)
#define VPAD   (NTILES * 128)   // 100096
#define SPLITS 32
#define TPS    25               // ceil(782/32)
#define XELEMS (N_ROWS * DIM)           // 2097152
#define WVALID ((size_t)VOCAB * DIM)    // 51200000
#define WBYTES ((size_t)VPAD * DIM)     // 51249152

typedef __attribute__((ext_vector_type(4))) int   i32x4;
typedef __attribute__((ext_vector_type(8))) int   i32x8;
typedef __attribute__((ext_vector_type(4))) float f32x4;

// ---------------- helpers ----------------

__device__ __forceinline__ void gload_lds16(const char* g, char* l) {
  // async global->LDS, 16B/lane; LDS dest = wave-uniform base + lane*16
  __builtin_amdgcn_global_load_lds(
      (const __attribute__((address_space(1))) unsigned int*)g,
      (__attribute__((address_space(3))) unsigned int*)l, 16, 0, 0);
}

__device__ __forceinline__ int pack4_fp8(float4 f, float sc) {
  int p = __builtin_amdgcn_cvt_pk_fp8_f32(f.x * sc, f.y * sc, 0, false);
  p = __builtin_amdgcn_cvt_pk_fp8_f32(f.z * sc, f.w * sc, p, true);
  return p;
}

// LDS rows are 128B = 8 chunks of 16B; logical chunk c of row r stored at physical
// chunk c ^ (r&7).  Frag reads (two 16B at logical chunks 2q,2q+1 of row fr) then
// hit every bank exactly 2x per 16-lane phase (2-way = free).
__device__ __forceinline__ i32x8 frag32(const char* p, int o0) {
  i32x4 lo = *(const i32x4*)(p + o0);
  i32x4 hi = *(const i32x4*)(p + (o0 ^ 16));
  return (i32x8){lo.x, lo.y, lo.z, lo.w, hi.x, hi.y, hi.z, hi.w};
}

// ---------------- fused conversion: x (scale 1) and W (value*32, MX scale 2^-5) -> fp8 ----------------

__global__ __launch_bounds__(256) void cvt_kernel(const float* __restrict__ x,
                                                  const float* __restrict__ W,
                                                  char* __restrict__ out8) {
  const size_t e = ((size_t)blockIdx.x * 256 + threadIdx.x) * 16;  // grid 13024: exact
  int4 o;
  if (e < (size_t)XELEMS) {
    const float4* s = (const float4*)(x + e);
    o.x = pack4_fp8(s[0], 1.f); o.y = pack4_fp8(s[1], 1.f);
    o.z = pack4_fp8(s[2], 1.f); o.w = pack4_fp8(s[3], 1.f);
  } else if (e - XELEMS < WVALID) {
    const float4* s = (const float4*)(W + (e - XELEMS));
    o.x = pack4_fp8(s[0], 32.f); o.y = pack4_fp8(s[1], 32.f);
    o.z = pack4_fp8(s[2], 32.f); o.w = pack4_fp8(s[3], 32.f);
  } else {
    o.x = 0; o.y = 0; o.z = 0; o.w = 0;   // vocab pad rows (also masked via bias=-inf)
  }
  *(int4*)(out8 + e) = o;
}

// ---------------- exact fp32 target logit: tgt[r] = x[r] . W[lb[r]] + b[lb[r]] ----------------

__global__ __launch_bounds__(256) void tgt_kernel(const float* __restrict__ x,
                                                  const int* __restrict__ lb,
                                                  const float* __restrict__ W,
                                                  const float* __restrict__ bias,
                                                  float* __restrict__ tgt) {
  const int wv = threadIdx.x >> 6;
  const int lane = threadIdx.x & 63;
  const int row = blockIdx.x * 4 + wv;   // grid 1024 -> 4096 rows exact
  const int t = lb[row];
  const float* xr = x + (size_t)row * DIM;
  const float* wr = W + (size_t)t * DIM;
  float s = 0.f;
#pragma unroll
  for (int i = 0; i < 8; ++i) s += xr[lane + i * 64] * wr[lane + i * 64];
#pragma unroll
  for (int m = 32; m; m >>= 1) s += __shfl_xor(s, m);
  if (lane == 0) tgt[row] = s + bias[t];
}

// ---------------- fused MX-fp8 GEMM + sum-exp ----------------
// grid: 1024 = 32 m-tiles x 32 V-splits (4 blocks/CU). block: 4 waves; wave w owns
// rows m0+32w..+31 as 2 row-frags x 8 col-frags of 16x16x128 (K=128, 4 K-steps over D=512).
// Scales: A identity (e8m0 127), B 2^-5 (122) undoing the W*32 quantization scale.

__global__ __launch_bounds__(256, 4) void lse_kernel(const char* __restrict__ xb,
                                                     const char* __restrict__ wb,
                                                     const float* __restrict__ bias,
                                                     float* __restrict__ spart) {
  __shared__ __align__(16) char ldsA[16384];   // 128 rows x 128B (swizzled chunks)
  __shared__ __align__(16) char ldsB[16384];

  const int bI = blockIdx.x;
  const int mtile = bI >> 5;
  const int s = bI & 31;
  const int m0 = mtile * 128;
  const int t0 = s * TPS;
  const int t1 = (t0 + TPS < NTILES) ? (t0 + TPS) : NTILES;

  const int tid  = threadIdx.x;
  const int lane = tid & 63;
  const int wv   = tid >> 6;
  const int srow = lane >> 3;                        // staging row-in-call 0..7
  const int schk = ((lane & 7) ^ (srow & 7)) << 4;   // swizzled global 16B chunk
  const int fr   = lane & 15;                        // frag row (A) / col (B,C)
  const int fq   = lane >> 4;                        // frag quad
  const int p0   = ((2 * fq) ^ (fr & 7)) << 4;       // first 16B phys offset in row

  float S[2][4];
#pragma unroll
  for (int i = 0; i < 2; ++i)
#pragma unroll
    for (int r = 0; r < 4; ++r) S[i][r] = 0.f;

  const char* gA = xb + (size_t)(m0 + 32 * wv + srow) * DIM + schk;
  char* lA = ldsA + (32 * wv) * 128;
  char* lB = ldsB + (32 * wv) * 128;
  const char* pAr0 = ldsA + (32 * wv + fr) * 128;
  const char* pAr1 = pAr0 + 16 * 128;

  const f32x4 zero4 = {0.f, 0.f, 0.f, 0.f};

  for (int t = t0; t < t1; ++t) {
    const int v0t = t * 128;
    const char* gB = wb + (size_t)(v0t + 32 * wv + srow) * DIM + schk;

    f32x4 acc[2][8];
#pragma unroll
    for (int i = 0; i < 2; ++i)
#pragma unroll
      for (int j = 0; j < 8; ++j) acc[i][j] = zero4;

    for (int ks = 0; ks < 4; ++ks) {
      const int k0 = ks * 128;
#pragma unroll
      for (int c = 0; c < 4; ++c) {
        gload_lds16(gA + k0 + c * 4096, lA + c * 1024);   // rows 32wv+8c..+7, k-window
        gload_lds16(gB + k0 + c * 4096, lB + c * 1024);
      }
      __syncthreads();  // staging complete
      i32x8 a0 = frag32(pAr0, p0);
      i32x8 a1 = frag32(pAr1, p0);
#pragma unroll
      for (int j = 0; j < 8; ++j) {
        i32x8 bf = frag32(ldsB + (16 * j + fr) * 128, p0);
        acc[0][j] = __builtin_amdgcn_mfma_scale_f32_16x16x128_f8f6f4(
            a0, bf, acc[0][j], 0, 0, 0, 127, 0, 122);
        acc[1][j] = __builtin_amdgcn_mfma_scale_f32_16x16x128_f8f6f4(
            a1, bf, acc[1][j], 0, 0, 0, 127, 0, 122);
      }
      __syncthreads();  // LDS reads done before next-step staging
    }

    // epilogue: C/D (16x16, shape-determined): col = v0t+16j+fr, row = m0+32wv+16i+4fq+r
    float badd[8];
#pragma unroll
    for (int j = 0; j < 8; ++j) {
      const int col = v0t + 16 * j + fr;
      badd[j] = (col < VOCAB) ? bias[col] : -INFINITY;  // exp(-inf)=0 masks tail cols
    }
#pragma unroll
    for (int i = 0; i < 2; ++i)
#pragma unroll
      for (int r = 0; r < 4; ++r) {
        float sum = 0.f;
#pragma unroll
        for (int j = 0; j < 8; ++j) sum += __expf(acc[i][j][r] + badd[j]);
        S[i][r] += sum;
      }
  }

  // reduce over the 16 lanes sharing each row group, write partials
#pragma unroll
  for (int i = 0; i < 2; ++i)
#pragma unroll
    for (int r = 0; r < 4; ++r) {
      float v = S[i][r];
      v += __shfl_xor(v, 1);
      v += __shfl_xor(v, 2);
      v += __shfl_xor(v, 4);
      v += __shfl_xor(v, 8);
      if (fr == 0) {
        const int row = m0 + 32 * wv + 16 * i + 4 * fq + r;
        spart[(size_t)row * SPLITS + s] = v;
      }
    }
}

// ---------------- combine: loss = mean(log(sum_s S_part) - tgt), atomic across 16 blocks ----------------

__global__ __launch_bounds__(256) void combine_kernel(const float* __restrict__ spart,
                                                      const float* __restrict__ tgt,
                                                      float* __restrict__ out) {
  const int r = blockIdx.x * 256 + threadIdx.x;   // grid 16 -> 4096 rows exact
  const float4* sp = (const float4*)(spart + (size_t)r * SPLITS);
  float st = 0.f;
#pragma unroll
  for (int i = 0; i < 8; ++i) { float4 v = sp[i]; st += (v.x + v.y) + (v.z + v.w); }
  float val = __logf(st) - tgt[r];
  __shared__ float red[256];
  red[threadIdx.x] = val;
  __syncthreads();
  for (int step = 128; step; step >>= 1) {
    if (threadIdx.x < step) red[threadIdx.x] += red[threadIdx.x + step];
    __syncthreads();
  }
  if (threadIdx.x == 0) atomicAdd(out, red[0] * (1.0f / (float)N_ROWS));
}

// ---------------- launch ----------------
// ws: x_fp8 [4096][512]B @0 | W_fp8 [100096][512]B | S_part [4096][32] f32 | tgt [4096] f32

extern "C" void kernel_launch(void* const* d_in, const int* in_sizes, int n_in,
                              void* d_out, int out_size, void* d_ws, size_t ws_size,
                              hipStream_t stream) {
  const float* x  = (const float*)d_in[0];
  const int*   lb = (const int*)d_in[1];
  const float* W  = (const float*)d_in[2];
  const float* b  = (const float*)d_in[3];
  float* out = (float*)d_out;

  char* ws = (char*)d_ws;
  const size_t OFF_W   = (size_t)XELEMS;          // 2097152
  const size_t OFF_SP  = OFF_W + WBYTES;          // 53346304
  const size_t OFF_TGT = OFF_SP + (size_t)N_ROWS * SPLITS * 4;
  char*  xb    = ws;
  char*  wb    = ws + OFF_W;
  float* spart = (float*)(ws + OFF_SP);
  float* tgt   = (float*)(ws + OFF_TGT);

  hipMemsetAsync(d_out, 0, sizeof(float), stream);
  cvt_kernel<<<13024, 256, 0, stream>>>(x, W, ws);
  tgt_kernel<<<1024, 256, 0, stream>>>(x, lb, W, b, tgt);
  lse_kernel<<<1024, 256, 0, stream>>>(xb, wb, b, spart);
  combine_kernel<<<16, 256, 0, stream>>>(spart, tgt, out);
}

// Round 4
// 1524.653 us; speedup vs baseline: 2.1717x; 2.1717x over previous
//
#include <hip/hip_runtime.h>
#include <hip/hip_bf16.h>
#include <math.h>

// ModelParallelSoftmaxLoss: loss = mean(logsumexp(x@W^T + b) - (x@W^T+b)[lb])
// N=4096, D=512, V=100000.
// R4: MX-fp8 (e4m3, K=128 mfma_scale) GEMM + max-free sum-exp. tgt logit exact fp32.
//     W quantized as W*32 with MX scale 2^-5 (avoids e4m3 subnormal range).
//     R3->R4: launch_bounds(256,4)->(256,2). The 128-reg unified VGPR cap made the
//     accumulators spill to scratch every K-step (6.4 GB HBM writes, MfmaUtil 2.7%).

#define N_ROWS 4096
#define DIM    512              // elements per row == bytes per row in fp8
#define VOCAB  100000
#define NTILES 782              // ceil(100000/128)
#define VPAD   (NTILES * 128)   // 100096
#define SPLITS 32
#define TPS    25               // ceil(782/32)
#define XELEMS (N_ROWS * DIM)           // 2097152
#define WVALID ((size_t)VOCAB * DIM)    // 51200000
#define WBYTES ((size_t)VPAD * DIM)     // 51249152

typedef __attribute__((ext_vector_type(4))) int   i32x4;
typedef __attribute__((ext_vector_type(8))) int   i32x8;
typedef __attribute__((ext_vector_type(4))) float f32x4;

// ---------------- helpers ----------------

__device__ __forceinline__ void gload_lds16(const char* g, char* l) {
  // async global->LDS, 16B/lane; LDS dest = wave-uniform base + lane*16
  __builtin_amdgcn_global_load_lds(
      (const __attribute__((address_space(1))) unsigned int*)g,
      (__attribute__((address_space(3))) unsigned int*)l, 16, 0, 0);
}

__device__ __forceinline__ int pack4_fp8(float4 f, float sc) {
  int p = __builtin_amdgcn_cvt_pk_fp8_f32(f.x * sc, f.y * sc, 0, false);
  p = __builtin_amdgcn_cvt_pk_fp8_f32(f.z * sc, f.w * sc, p, true);
  return p;
}

// LDS rows are 128B = 8 chunks of 16B; logical chunk c of row r stored at physical
// chunk c ^ (r&7).  Frag reads (two 16B at logical chunks 2q,2q+1 of row fr) then
// hit every bank exactly 2x per 16-lane phase (2-way = free).
__device__ __forceinline__ i32x8 frag32(const char* p, int o0) {
  i32x4 lo = *(const i32x4*)(p + o0);
  i32x4 hi = *(const i32x4*)(p + (o0 ^ 16));
  return (i32x8){lo.x, lo.y, lo.z, lo.w, hi.x, hi.y, hi.z, hi.w};
}

// ---------------- fused conversion: x (scale 1) and W (value*32, MX scale 2^-5) -> fp8 ----------------

__global__ __launch_bounds__(256) void cvt_kernel(const float* __restrict__ x,
                                                  const float* __restrict__ W,
                                                  char* __restrict__ out8) {
  const size_t e = ((size_t)blockIdx.x * 256 + threadIdx.x) * 16;  // grid 13024: exact
  int4 o;
  if (e < (size_t)XELEMS) {
    const float4* s = (const float4*)(x + e);
    o.x = pack4_fp8(s[0], 1.f); o.y = pack4_fp8(s[1], 1.f);
    o.z = pack4_fp8(s[2], 1.f); o.w = pack4_fp8(s[3], 1.f);
  } else if (e - XELEMS < WVALID) {
    const float4* s = (const float4*)(W + (e - XELEMS));
    o.x = pack4_fp8(s[0], 32.f); o.y = pack4_fp8(s[1], 32.f);
    o.z = pack4_fp8(s[2], 32.f); o.w = pack4_fp8(s[3], 32.f);
  } else {
    o.x = 0; o.y = 0; o.z = 0; o.w = 0;   // vocab pad rows (also masked via bias=-inf)
  }
  *(int4*)(out8 + e) = o;
}

// ---------------- exact fp32 target logit: tgt[r] = x[r] . W[lb[r]] + b[lb[r]] ----------------

__global__ __launch_bounds__(256) void tgt_kernel(const float* __restrict__ x,
                                                  const int* __restrict__ lb,
                                                  const float* __restrict__ W,
                                                  const float* __restrict__ bias,
                                                  float* __restrict__ tgt) {
  const int wv = threadIdx.x >> 6;
  const int lane = threadIdx.x & 63;
  const int row = blockIdx.x * 4 + wv;   // grid 1024 -> 4096 rows exact
  const int t = lb[row];
  const float* xr = x + (size_t)row * DIM;
  const float* wr = W + (size_t)t * DIM;
  float s = 0.f;
#pragma unroll
  for (int i = 0; i < 8; ++i) s += xr[lane + i * 64] * wr[lane + i * 64];
#pragma unroll
  for (int m = 32; m; m >>= 1) s += __shfl_xor(s, m);
  if (lane == 0) tgt[row] = s + bias[t];
}

// ---------------- fused MX-fp8 GEMM + sum-exp ----------------
// grid: 1024 = 32 m-tiles x 32 V-splits. block: 4 waves; wave w owns rows m0+32w..+31
// as 2 row-frags x 8 col-frags of 16x16x128 (K=128, 4 K-steps over D=512).
// Scales: A identity (e8m0 127), B 2^-5 (122) undoing the W*32 quantization scale.

__global__ __launch_bounds__(256, 2) void lse_kernel(const char* __restrict__ xb,
                                                     const char* __restrict__ wb,
                                                     const float* __restrict__ bias,
                                                     float* __restrict__ spart) {
  __shared__ __align__(16) char ldsA[16384];   // 128 rows x 128B (swizzled chunks)
  __shared__ __align__(16) char ldsB[16384];

  const int bI = blockIdx.x;
  const int mtile = bI >> 5;
  const int s = bI & 31;
  const int m0 = mtile * 128;
  const int t0 = s * TPS;
  const int t1 = (t0 + TPS < NTILES) ? (t0 + TPS) : NTILES;

  const int tid  = threadIdx.x;
  const int lane = tid & 63;
  const int wv   = tid >> 6;
  const int srow = lane >> 3;                        // staging row-in-call 0..7
  const int schk = ((lane & 7) ^ (srow & 7)) << 4;   // swizzled global 16B chunk
  const int fr   = lane & 15;                        // frag row (A) / col (B,C)
  const int fq   = lane >> 4;                        // frag quad
  const int p0   = ((2 * fq) ^ (fr & 7)) << 4;       // first 16B phys offset in row

  float S[2][4];
#pragma unroll
  for (int i = 0; i < 2; ++i)
#pragma unroll
    for (int r = 0; r < 4; ++r) S[i][r] = 0.f;

  const char* gA = xb + (size_t)(m0 + 32 * wv + srow) * DIM + schk;
  char* lA = ldsA + (32 * wv) * 128;
  char* lB = ldsB + (32 * wv) * 128;
  const char* pAr0 = ldsA + (32 * wv + fr) * 128;
  const char* pAr1 = pAr0 + 16 * 128;

  const f32x4 zero4 = {0.f, 0.f, 0.f, 0.f};

  for (int t = t0; t < t1; ++t) {
    const int v0t = t * 128;
    const char* gB = wb + (size_t)(v0t + 32 * wv + srow) * DIM + schk;

    f32x4 acc[2][8];
#pragma unroll
    for (int i = 0; i < 2; ++i)
#pragma unroll
      for (int j = 0; j < 8; ++j) acc[i][j] = zero4;

    for (int ks = 0; ks < 4; ++ks) {
      const int k0 = ks * 128;
#pragma unroll
      for (int c = 0; c < 4; ++c) {
        gload_lds16(gA + k0 + c * 4096, lA + c * 1024);   // rows 32wv+8c..+7, k-window
        gload_lds16(gB + k0 + c * 4096, lB + c * 1024);
      }
      __syncthreads();  // staging complete
      i32x8 a0 = frag32(pAr0, p0);
      i32x8 a1 = frag32(pAr1, p0);
#pragma unroll
      for (int j = 0; j < 8; ++j) {
        i32x8 bf = frag32(ldsB + (16 * j + fr) * 128, p0);
        acc[0][j] = __builtin_amdgcn_mfma_scale_f32_16x16x128_f8f6f4(
            a0, bf, acc[0][j], 0, 0, 0, 127, 0, 122);
        acc[1][j] = __builtin_amdgcn_mfma_scale_f32_16x16x128_f8f6f4(
            a1, bf, acc[1][j], 0, 0, 0, 127, 0, 122);
      }
      __syncthreads();  // LDS reads done before next-step staging
    }

    // epilogue: C/D (16x16, shape-determined): col = v0t+16j+fr, row = m0+32wv+16i+4fq+r
    float badd[8];
#pragma unroll
    for (int j = 0; j < 8; ++j) {
      const int col = v0t + 16 * j + fr;
      badd[j] = (col < VOCAB) ? bias[col] : -INFINITY;  // exp(-inf)=0 masks tail cols
    }
#pragma unroll
    for (int i = 0; i < 2; ++i)
#pragma unroll
      for (int r = 0; r < 4; ++r) {
        float sum = 0.f;
#pragma unroll
        for (int j = 0; j < 8; ++j) sum += __expf(acc[i][j][r] + badd[j]);
        S[i][r] += sum;
      }
  }

  // reduce over the 16 lanes sharing each row group, write partials
#pragma unroll
  for (int i = 0; i < 2; ++i)
#pragma unroll
    for (int r = 0; r < 4; ++r) {
      float v = S[i][r];
      v += __shfl_xor(v, 1);
      v += __shfl_xor(v, 2);
      v += __shfl_xor(v, 4);
      v += __shfl_xor(v, 8);
      if (fr == 0) {
        const int row = m0 + 32 * wv + 16 * i + 4 * fq + r;
        spart[(size_t)row * SPLITS + s] = v;
      }
    }
}

// ---------------- combine: loss = mean(log(sum_s S_part) - tgt), atomic across 16 blocks ----------------

__global__ __launch_bounds__(256) void combine_kernel(const float* __restrict__ spart,
                                                      const float* __restrict__ tgt,
                                                      float* __restrict__ out) {
  const int r = blockIdx.x * 256 + threadIdx.x;   // grid 16 -> 4096 rows exact
  const float4* sp = (const float4*)(spart + (size_t)r * SPLITS);
  float st = 0.f;
#pragma unroll
  for (int i = 0; i < 8; ++i) { float4 v = sp[i]; st += (v.x + v.y) + (v.z + v.w); }
  float val = __logf(st) - tgt[r];
  __shared__ float red[256];
  red[threadIdx.x] = val;
  __syncthreads();
  for (int step = 128; step; step >>= 1) {
    if (threadIdx.x < step) red[threadIdx.x] += red[threadIdx.x + step];
    __syncthreads();
  }
  if (threadIdx.x == 0) atomicAdd(out, red[0] * (1.0f / (float)N_ROWS));
}

// ---------------- launch ----------------
// ws: x_fp8 [4096][512]B @0 | W_fp8 [100096][512]B | S_part [4096][32] f32 | tgt [4096] f32

extern "C" void kernel_launch(void* const* d_in, const int* in_sizes, int n_in,
                              void* d_out, int out_size, void* d_ws, size_t ws_size,
                              hipStream_t stream) {
  const float* x  = (const float*)d_in[0];
  const int*   lb = (const int*)d_in[1];
  const float* W  = (const float*)d_in[2];
  const float* b  = (const float*)d_in[3];
  float* out = (float*)d_out;

  char* ws = (char*)d_ws;
  const size_t OFF_W   = (size_t)XELEMS;          // 2097152
  const size_t OFF_SP  = OFF_W + WBYTES;          // 53346304
  const size_t OFF_TGT = OFF_SP + (size_t)N_ROWS * SPLITS * 4;
  char*  xb    = ws;
  char*  wb    = ws + OFF_W;
  float* spart = (float*)(ws + OFF_SP);
  float* tgt   = (float*)(ws + OFF_TGT);

  hipMemsetAsync(d_out, 0, sizeof(float), stream);
  cvt_kernel<<<13024, 256, 0, stream>>>(x, W, ws);
  tgt_kernel<<<1024, 256, 0, stream>>>(x, lb, W, b, tgt);
  lse_kernel<<<1024, 256, 0, stream>>>(xb, wb, b, spart);
  combine_kernel<<<16, 256, 0, stream>>>(spart, tgt, out);
}

// Round 5
// 912.202 us; speedup vs baseline: 3.6298x; 1.6714x over previous
//
#include <hip/hip_runtime.h>
#include <hip/hip_bf16.h>
#include <math.h>

// ModelParallelSoftmaxLoss: loss = mean(logsumexp(x@W^T + b) - (x@W^T+b)[lb])
// N=4096, D=512, V=100000.
// R5: MX-fp8 (e4m3, K=128 mfma_scale) GEMM + max-free sum-exp. tgt logit exact fp32.
//     W quantized as W*32 with MX scale 2^-5 (avoids e4m3 subnormal range).
//     R4->R5: (a) launch_bounds(256,1) — the (256,2) 256-reg unified budget split
//     128 arch + 128 AGPR; ~160 arch demand (8 hoisted B-frags) still spilled 2.4 GB.
//     (b) fragment-order LDS layout: group g (16 rows) at g*2048, slot = half*1024 +
//     frag_lane*16. Frag reads = base + lane*16 (+1024) -> stride-16, conflict-free,
//     one addr VGPR + immediates. Staging permutes on the global side instead.

#define N_ROWS 4096
#define DIM    512              // elements per row == bytes per row in fp8
#define VOCAB  100000
#define NTILES 782              // ceil(100000/128)
#define VPAD   (NTILES * 128)   // 100096
#define SPLITS 32
#define TPS    25               // ceil(782/32)
#define XELEMS (N_ROWS * DIM)           // 2097152
#define WVALID ((size_t)VOCAB * DIM)    // 51200000
#define WBYTES ((size_t)VPAD * DIM)     // 51249152

typedef __attribute__((ext_vector_type(4))) int   i32x4;
typedef __attribute__((ext_vector_type(8))) int   i32x8;
typedef __attribute__((ext_vector_type(4))) float f32x4;

// ---------------- helpers ----------------

__device__ __forceinline__ void gload_lds16(const char* g, char* l) {
  // async global->LDS, 16B/lane; LDS dest = wave-uniform base + lane*16
  __builtin_amdgcn_global_load_lds(
      (const __attribute__((address_space(1))) unsigned int*)g,
      (__attribute__((address_space(3))) unsigned int*)l, 16, 0, 0);
}

__device__ __forceinline__ int pack4_fp8(float4 f, float sc) {
  int p = __builtin_amdgcn_cvt_pk_fp8_f32(f.x * sc, f.y * sc, 0, false);
  p = __builtin_amdgcn_cvt_pk_fp8_f32(f.z * sc, f.w * sc, p, true);
  return p;
}

// read one 32B fragment stored fragment-order: lo at base, hi at base+1024
__device__ __forceinline__ i32x8 frag32(const char* base) {
  i32x4 lo = *(const i32x4*)(base);
  i32x4 hi = *(const i32x4*)(base + 1024);
  return (i32x8){lo.x, lo.y, lo.z, lo.w, hi.x, hi.y, hi.z, hi.w};
}

// ---------------- fused conversion: x (scale 1) and W (value*32, MX scale 2^-5) -> fp8 ----------------

__global__ __launch_bounds__(256) void cvt_kernel(const float* __restrict__ x,
                                                  const float* __restrict__ W,
                                                  char* __restrict__ out8) {
  const size_t e = ((size_t)blockIdx.x * 256 + threadIdx.x) * 16;  // grid 13024: exact
  int4 o;
  if (e < (size_t)XELEMS) {
    const float4* s = (const float4*)(x + e);
    o.x = pack4_fp8(s[0], 1.f); o.y = pack4_fp8(s[1], 1.f);
    o.z = pack4_fp8(s[2], 1.f); o.w = pack4_fp8(s[3], 1.f);
  } else if (e - XELEMS < WVALID) {
    const float4* s = (const float4*)(W + (e - XELEMS));
    o.x = pack4_fp8(s[0], 32.f); o.y = pack4_fp8(s[1], 32.f);
    o.z = pack4_fp8(s[2], 32.f); o.w = pack4_fp8(s[3], 32.f);
  } else {
    o.x = 0; o.y = 0; o.z = 0; o.w = 0;   // vocab pad rows (also masked via bias=-inf)
  }
  *(int4*)(out8 + e) = o;
}

// ---------------- exact fp32 target logit: tgt[r] = x[r] . W[lb[r]] + b[lb[r]] ----------------

__global__ __launch_bounds__(256) void tgt_kernel(const float* __restrict__ x,
                                                  const int* __restrict__ lb,
                                                  const float* __restrict__ W,
                                                  const float* __restrict__ bias,
                                                  float* __restrict__ tgt) {
  const int wv = threadIdx.x >> 6;
  const int lane = threadIdx.x & 63;
  const int row = blockIdx.x * 4 + wv;   // grid 1024 -> 4096 rows exact
  const int t = lb[row];
  const float* xr = x + (size_t)row * DIM;
  const float* wr = W + (size_t)t * DIM;
  float s = 0.f;
#pragma unroll
  for (int i = 0; i < 8; ++i) s += xr[lane + i * 64] * wr[lane + i * 64];
#pragma unroll
  for (int m = 32; m; m >>= 1) s += __shfl_xor(s, m);
  if (lane == 0) tgt[row] = s + bias[t];
}

// ---------------- fused MX-fp8 GEMM + sum-exp ----------------
// grid: 1024 = 32 m-tiles x 32 V-splits. block: 4 waves; wave w owns rows m0+32w..+31
// as 2 row-frags x 8 col-frags of 16x16x128 (K=128, 4 K-steps over D=512).
// LDS tile (A or B): 8 groups of 16 rows; group g at g*2048; slot = half*1024 +
// (fq*16+fr)*16 holds row (16g+fr), k-bytes fq*32 + half*16 .. +15 of the k-window.
// Staging: wave wv loads groups 2wv,2wv+1 of both tiles (8 calls of 1KB per ks);
// global source per lane: row = lane&15 (x512B), kchunk = lane>>4 (x32B), +16 for half 1.
// Scales: A identity (e8m0 127), B 2^-5 (122) undoing the W*32 quantization scale.

__global__ __launch_bounds__(256, 1) void lse_kernel(const char* __restrict__ xb,
                                                     const char* __restrict__ wb,
                                                     const float* __restrict__ bias,
                                                     float* __restrict__ spart) {
  __shared__ __align__(16) char ldsA[16384];
  __shared__ __align__(16) char ldsB[16384];

  const int bI = blockIdx.x;
  const int mtile = bI >> 5;
  const int s = bI & 31;
  const int m0 = mtile * 128;
  const int t0 = s * TPS;
  const int t1 = (t0 + TPS < NTILES) ? (t0 + TPS) : NTILES;

  const int tid  = threadIdx.x;
  const int lane = tid & 63;
  const int wv   = tid >> 6;
  const int fr   = lane & 15;        // frag row (A) / col (B,C); staging row-in-group
  const int fq   = lane >> 4;        // frag quad; staging k-chunk

  // staging global-side per-lane offset: row fr (512B), k-chunk fq (32B)
  const int goff = fr * DIM + fq * 32;
  // per-wave A sources for groups 2wv (rows 32wv+fr) and 2wv+1 (+16 rows)
  const char* gA0 = xb + (size_t)(m0 + 32 * wv + fr) * DIM + fq * 32;
  const char* gA1 = gA0 + 16 * DIM;
  char* dA = ldsA + wv * 4096;       // groups 2wv, 2wv+1 = 4KB
  char* dB = ldsB + wv * 4096;

  // frag-read base: slot = lane*16 within each (group,half) KB
  const char* fA = ldsA + (2 * wv) * 2048 + lane * 16;  // +i*2048 for row-frag i
  const char* fB = ldsB + lane * 16;                    // +j*2048 for col-frag j

  float S[2][4];
#pragma unroll
  for (int i = 0; i < 2; ++i)
#pragma unroll
    for (int r = 0; r < 4; ++r) S[i][r] = 0.f;

  const f32x4 zero4 = {0.f, 0.f, 0.f, 0.f};

  for (int t = t0; t < t1; ++t) {
    const int v0t = t * 128;
    const char* gB0 = wb + (size_t)(v0t + 32 * wv) * DIM + goff;
    const char* gB1 = gB0 + 16 * DIM;

    f32x4 acc[2][8];
#pragma unroll
    for (int i = 0; i < 2; ++i)
#pragma unroll
      for (int j = 0; j < 8; ++j) acc[i][j] = zero4;

    for (int ks = 0; ks < 4; ++ks) {
      const int k0 = ks * 128;
      gload_lds16(gA0 + k0,      dA);           // g=2wv,   half 0
      gload_lds16(gA0 + k0 + 16, dA + 1024);    // g=2wv,   half 1
      gload_lds16(gA1 + k0,      dA + 2048);    // g=2wv+1, half 0
      gload_lds16(gA1 + k0 + 16, dA + 3072);
      gload_lds16(gB0 + k0,      dB);
      gload_lds16(gB0 + k0 + 16, dB + 1024);
      gload_lds16(gB1 + k0,      dB + 2048);
      gload_lds16(gB1 + k0 + 16, dB + 3072);
      __syncthreads();  // staging complete
      i32x8 a0 = frag32(fA);
      i32x8 a1 = frag32(fA + 2048);
#pragma unroll
      for (int j = 0; j < 8; ++j) {
        i32x8 bf = frag32(fB + j * 2048);
        acc[0][j] = __builtin_amdgcn_mfma_scale_f32_16x16x128_f8f6f4(
            a0, bf, acc[0][j], 0, 0, 0, 127, 0, 122);
        acc[1][j] = __builtin_amdgcn_mfma_scale_f32_16x16x128_f8f6f4(
            a1, bf, acc[1][j], 0, 0, 0, 127, 0, 122);
      }
      __syncthreads();  // LDS reads done before next-step staging
    }

    // epilogue: C/D (16x16, shape-determined): col = v0t+16j+fr, row = m0+32wv+16i+4fq+r
    float badd[8];
#pragma unroll
    for (int j = 0; j < 8; ++j) {
      const int col = v0t + 16 * j + fr;
      badd[j] = (col < VOCAB) ? bias[col] : -INFINITY;  // exp(-inf)=0 masks tail cols
    }
#pragma unroll
    for (int i = 0; i < 2; ++i)
#pragma unroll
      for (int r = 0; r < 4; ++r) {
        float sum = 0.f;
#pragma unroll
        for (int j = 0; j < 8; ++j) sum += __expf(acc[i][j][r] + badd[j]);
        S[i][r] += sum;
      }
  }

  // reduce over the 16 lanes sharing each row group, write partials
#pragma unroll
  for (int i = 0; i < 2; ++i)
#pragma unroll
    for (int r = 0; r < 4; ++r) {
      float v = S[i][r];
      v += __shfl_xor(v, 1);
      v += __shfl_xor(v, 2);
      v += __shfl_xor(v, 4);
      v += __shfl_xor(v, 8);
      if (fr == 0) {
        const int row = m0 + 32 * wv + 16 * i + 4 * (lane >> 4) + r;
        spart[(size_t)row * SPLITS + s] = v;
      }
    }
}

// ---------------- combine: loss = mean(log(sum_s S_part) - tgt), atomic across 16 blocks ----------------

__global__ __launch_bounds__(256) void combine_kernel(const float* __restrict__ spart,
                                                      const float* __restrict__ tgt,
                                                      float* __restrict__ out) {
  const int r = blockIdx.x * 256 + threadIdx.x;   // grid 16 -> 4096 rows exact
  const float4* sp = (const float4*)(spart + (size_t)r * SPLITS);
  float st = 0.f;
#pragma unroll
  for (int i = 0; i < 8; ++i) { float4 v = sp[i]; st += (v.x + v.y) + (v.z + v.w); }
  float val = __logf(st) - tgt[r];
  __shared__ float red[256];
  red[threadIdx.x] = val;
  __syncthreads();
  for (int step = 128; step; step >>= 1) {
    if (threadIdx.x < step) red[threadIdx.x] += red[threadIdx.x + step];
    __syncthreads();
  }
  if (threadIdx.x == 0) atomicAdd(out, red[0] * (1.0f / (float)N_ROWS));
}

// ---------------- launch ----------------
// ws: x_fp8 [4096][512]B @0 | W_fp8 [100096][512]B | S_part [4096][32] f32 | tgt [4096] f32

extern "C" void kernel_launch(void* const* d_in, const int* in_sizes, int n_in,
                              void* d_out, int out_size, void* d_ws, size_t ws_size,
                              hipStream_t stream) {
  const float* x  = (const float*)d_in[0];
  const int*   lb = (const int*)d_in[1];
  const float* W  = (const float*)d_in[2];
  const float* b  = (const float*)d_in[3];
  float* out = (float*)d_out;

  char* ws = (char*)d_ws;
  const size_t OFF_W   = (size_t)XELEMS;          // 2097152
  const size_t OFF_SP  = OFF_W + WBYTES;          // 53346304
  const size_t OFF_TGT = OFF_SP + (size_t)N_ROWS * SPLITS * 4;
  char*  xb    = ws;
  char*  wb    = ws + OFF_W;
  float* spart = (float*)(ws + OFF_SP);
  float* tgt   = (float*)(ws + OFF_TGT);

  hipMemsetAsync(d_out, 0, sizeof(float), stream);
  cvt_kernel<<<13024, 256, 0, stream>>>(x, W, ws);
  tgt_kernel<<<1024, 256, 0, stream>>>(x, lb, W, b, tgt);
  lse_kernel<<<1024, 256, 0, stream>>>(xb, wb, b, spart);
  combine_kernel<<<16, 256, 0, stream>>>(spart, tgt, out);
}

// Round 6
// 764.895 us; speedup vs baseline: 4.3289x; 1.1926x over previous
//
#include <hip/hip_runtime.h>
#include <hip/hip_bf16.h>
#include <math.h>

// ModelParallelSoftmaxLoss: loss = mean(logsumexp(x@W^T + b) - (x@W^T+b)[lb])
// N=4096, D=512, V=100000.
// R6: MX-fp8 (e4m3, K=128 mfma_scale) GEMM + max-free sum-exp. tgt logit exact fp32.
//     R5->R6 (R5 was latency-bound at 1 block/CU: MfmaUtil 13%, all pipes idle):
//     (a) A held in registers for the whole kernel (32 rows x 512B = 64 VGPR/wave,
//         loaded once from global) — no A staging, no A ds_reads in the K-loop.
//     (b) B-only LDS, double-buffered 2x16KB, ONE barrier per K-step: staging for
//         step u+1 issues before compute(u); the vmcnt(0) drain at the bottom
//         __syncthreads lands ~550 MFMA-cycles after issue -> latency covered.
//     (c) flat step loop across tiles (epilogue overlaps next tile's staging).

#define N_ROWS 4096
#define DIM    512              // elements per row == bytes per row in fp8
#define VOCAB  100000
#define NTILES 782              // ceil(100000/128)
#define VPAD   (NTILES * 128)   // 100096
#define SPLITS 32
#define TPS    25               // ceil(782/32)
#define XELEMS (N_ROWS * DIM)           // 2097152
#define WVALID ((size_t)VOCAB * DIM)    // 51200000
#define WBYTES ((size_t)VPAD * DIM)     // 51249152

typedef __attribute__((ext_vector_type(4))) int   i32x4;
typedef __attribute__((ext_vector_type(8))) int   i32x8;
typedef __attribute__((ext_vector_type(4))) float f32x4;

// ---------------- helpers ----------------

__device__ __forceinline__ void gload_lds16(const char* g, char* l) {
  // async global->LDS, 16B/lane; LDS dest = wave-uniform base + lane*16
  __builtin_amdgcn_global_load_lds(
      (const __attribute__((address_space(1))) unsigned int*)g,
      (__attribute__((address_space(3))) unsigned int*)l, 16, 0, 0);
}

__device__ __forceinline__ int pack4_fp8(float4 f, float sc) {
  int p = __builtin_amdgcn_cvt_pk_fp8_f32(f.x * sc, f.y * sc, 0, false);
  p = __builtin_amdgcn_cvt_pk_fp8_f32(f.z * sc, f.w * sc, p, true);
  return p;
}

// read one 32B fragment stored fragment-order: lo at base, hi at base+1024
__device__ __forceinline__ i32x8 frag32(const char* base) {
  i32x4 lo = *(const i32x4*)(base);
  i32x4 hi = *(const i32x4*)(base + 1024);
  return (i32x8){lo.x, lo.y, lo.z, lo.w, hi.x, hi.y, hi.z, hi.w};
}

// ---------------- fused conversion: x (scale 1) and W (value*32, MX scale 2^-5) -> fp8 ----------------

__global__ __launch_bounds__(256) void cvt_kernel(const float* __restrict__ x,
                                                  const float* __restrict__ W,
                                                  char* __restrict__ out8) {
  const size_t e = ((size_t)blockIdx.x * 256 + threadIdx.x) * 16;  // grid 13024: exact
  int4 o;
  if (e < (size_t)XELEMS) {
    const float4* s = (const float4*)(x + e);
    o.x = pack4_fp8(s[0], 1.f); o.y = pack4_fp8(s[1], 1.f);
    o.z = pack4_fp8(s[2], 1.f); o.w = pack4_fp8(s[3], 1.f);
  } else if (e - XELEMS < WVALID) {
    const float4* s = (const float4*)(W + (e - XELEMS));
    o.x = pack4_fp8(s[0], 32.f); o.y = pack4_fp8(s[1], 32.f);
    o.z = pack4_fp8(s[2], 32.f); o.w = pack4_fp8(s[3], 32.f);
  } else {
    o.x = 0; o.y = 0; o.z = 0; o.w = 0;   // vocab pad rows (also masked via bias=-inf)
  }
  *(int4*)(out8 + e) = o;
}

// ---------------- exact fp32 target logit: tgt[r] = x[r] . W[lb[r]] + b[lb[r]] ----------------

__global__ __launch_bounds__(256) void tgt_kernel(const float* __restrict__ x,
                                                  const int* __restrict__ lb,
                                                  const float* __restrict__ W,
                                                  const float* __restrict__ bias,
                                                  float* __restrict__ tgt) {
  const int wv = threadIdx.x >> 6;
  const int lane = threadIdx.x & 63;
  const int row = blockIdx.x * 4 + wv;   // grid 1024 -> 4096 rows exact
  const int t = lb[row];
  const float* xr = x + (size_t)row * DIM;
  const float* wr = W + (size_t)t * DIM;
  float s = 0.f;
#pragma unroll
  for (int i = 0; i < 8; ++i) s += xr[lane + i * 64] * wr[lane + i * 64];
#pragma unroll
  for (int m = 32; m; m >>= 1) s += __shfl_xor(s, m);
  if (lane == 0) tgt[row] = s + bias[t];
}

// ---------------- fused MX-fp8 GEMM + sum-exp ----------------
// grid: 1024 = 32 m-tiles x 32 V-splits. block: 4 waves; wave w owns rows m0+32w..+31
// as 2 row-frags x 8 col-frags of 16x16x128 (K=128, 4 K-steps over D=512).
// A frag (held in regs): lane(fr,fq) = row fr, k-bytes fq*32..+31 of each 128B K-window.
// B LDS (per buffer, 16KB): 8 col-groups of 16 rows; group g at g*2048; slot =
// half*1024 + lane*16 holds row 16g+fr, k-bytes fq*32+half*16..+15.
// Scales: A identity (e8m0 127), B 2^-5 (122) undoing the W*32 quantization scale.

__global__ __launch_bounds__(256, 1) void lse_kernel(const char* __restrict__ xb,
                                                     const char* __restrict__ wb,
                                                     const float* __restrict__ bias,
                                                     float* __restrict__ spart) {
  __shared__ __align__(16) char ldsB[2][16384];

  const int bI = blockIdx.x;
  const int mtile = bI >> 5;
  const int s = bI & 31;
  const int m0 = mtile * 128;
  const int t0 = s * TPS;
  const int t1 = (t0 + TPS < NTILES) ? (t0 + TPS) : NTILES;
  const int NSTEP = (t1 - t0) * 4;

  const int tid  = threadIdx.x;
  const int lane = tid & 63;
  const int wv   = tid >> 6;
  const int fr   = lane & 15;        // frag row (A) / col (B,C); staging row-in-group
  const int fq   = lane >> 4;        // frag quad; staging k-chunk

  // ---- load A fragments into registers (64 VGPRs) ----
  i32x8 Aa[2][4];
  {
    const char* ax = xb + (size_t)(m0 + 32 * wv + fr) * DIM + fq * 32;
#pragma unroll
    for (int i = 0; i < 2; ++i)
#pragma unroll
      for (int ks = 0; ks < 4; ++ks) {
        const char* p = ax + i * (16 * DIM) + ks * 128;
        i32x4 lo = *(const i32x4*)p;
        i32x4 hi = *(const i32x4*)(p + 16);
        Aa[i][ks] = (i32x8){lo.x, lo.y, lo.z, lo.w, hi.x, hi.y, hi.z, hi.w};
      }
  }

  // per-wave B staging: groups 2wv, 2wv+1 (4 calls of 1KB per K-step)
  const size_t bRowOff = (size_t)(32 * wv + fr) * DIM + fq * 32;
  char* const dB0 = &ldsB[0][wv * 4096];
  char* const dB1 = &ldsB[1][wv * 4096];

  float S[2][4];
#pragma unroll
  for (int i = 0; i < 2; ++i)
#pragma unroll
    for (int r = 0; r < 4; ++r) S[i][r] = 0.f;

  f32x4 acc[2][8];
#pragma unroll
  for (int i = 0; i < 2; ++i)
#pragma unroll
    for (int j = 0; j < 8; ++j) acc[i][j] = (f32x4){0.f, 0.f, 0.f, 0.f};

  // stage step u into buffer buf
  auto stageB = [&](int u, char* d) {
    const int tt = t0 + (u >> 2);
    const char* src = wb + (size_t)tt * (128 * DIM) + bRowOff + (u & 3) * 128;
    gload_lds16(src,            d);           // group 2wv,   half 0
    gload_lds16(src + 16,       d + 1024);    // group 2wv,   half 1
    gload_lds16(src + 16 * DIM,      d + 2048);   // group 2wv+1, half 0
    gload_lds16(src + 16 * DIM + 16, d + 3072);   // group 2wv+1, half 1
  };

  stageB(0, dB0);
  __syncthreads();   // buf0 ready (vmcnt drain + barrier)

  for (int u = 0; u < NSTEP; ++u) {
    if (u + 1 < NSTEP) stageB(u + 1, ((u + 1) & 1) ? dB1 : dB0);  // in flight during compute

    const char* fB = &ldsB[u & 1][lane * 16];
    const int ks = u & 3;
    const i32x8 a0 = Aa[0][ks];
    const i32x8 a1 = Aa[1][ks];
#pragma unroll
    for (int j = 0; j < 8; ++j) {
      i32x8 bf = frag32(fB + j * 2048);
      acc[0][j] = __builtin_amdgcn_mfma_scale_f32_16x16x128_f8f6f4(
          a0, bf, acc[0][j], 0, 0, 0, 127, 0, 122);
      acc[1][j] = __builtin_amdgcn_mfma_scale_f32_16x16x128_f8f6f4(
          a1, bf, acc[1][j], 0, 0, 0, 127, 0, 122);
    }

    if (ks == 3) {
      // epilogue for tile t = t0 + (u>>2):
      // C/D (16x16, shape-determined): col = v0t+16j+fr, row = m0+32wv+16i+4fq+r
      const int v0t = (t0 + (u >> 2)) * 128;
      float badd[8];
#pragma unroll
      for (int j = 0; j < 8; ++j) {
        const int col = v0t + 16 * j + fr;
        badd[j] = (col < VOCAB) ? bias[col] : -INFINITY;  // exp(-inf)=0 masks tail cols
      }
#pragma unroll
      for (int i = 0; i < 2; ++i)
#pragma unroll
        for (int r = 0; r < 4; ++r) {
          float sum = 0.f;
#pragma unroll
          for (int j = 0; j < 8; ++j) sum += __expf(acc[i][j][r] + badd[j]);
          S[i][r] += sum;
        }
#pragma unroll
      for (int i = 0; i < 2; ++i)
#pragma unroll
        for (int j = 0; j < 8; ++j) acc[i][j] = (f32x4){0.f, 0.f, 0.f, 0.f};
    }

    __syncthreads();   // drains staging vmcnt (buf[u+1] ready) + protects buf[u] reuse
  }

  // reduce over the 16 lanes sharing each row group, write partials
#pragma unroll
  for (int i = 0; i < 2; ++i)
#pragma unroll
    for (int r = 0; r < 4; ++r) {
      float v = S[i][r];
      v += __shfl_xor(v, 1);
      v += __shfl_xor(v, 2);
      v += __shfl_xor(v, 4);
      v += __shfl_xor(v, 8);
      if (fr == 0) {
        const int row = m0 + 32 * wv + 16 * i + 4 * fq + r;
        spart[(size_t)row * SPLITS + s] = v;
      }
    }
}

// ---------------- combine: loss = mean(log(sum_s S_part) - tgt), single block ----------------

__global__ __launch_bounds__(256) void combine_kernel(const float* __restrict__ spart,
                                                      const float* __restrict__ tgt,
                                                      float* __restrict__ out) {
  __shared__ float red[256];
  float local = 0.f;
  for (int r = threadIdx.x; r < N_ROWS; r += 256) {
    const float4* sp = (const float4*)(spart + (size_t)r * SPLITS);
    float st = 0.f;
#pragma unroll
    for (int i = 0; i < 8; ++i) { float4 v = sp[i]; st += (v.x + v.y) + (v.z + v.w); }
    local += __logf(st) - tgt[r];
  }
  red[threadIdx.x] = local;
  __syncthreads();
  for (int step = 128; step; step >>= 1) {
    if (threadIdx.x < step) red[threadIdx.x] += red[threadIdx.x + step];
    __syncthreads();
  }
  if (threadIdx.x == 0) out[0] = red[0] * (1.0f / (float)N_ROWS);
}

// ---------------- launch ----------------
// ws: x_fp8 [4096][512]B @0 | W_fp8 [100096][512]B | S_part [4096][32] f32 | tgt [4096] f32

extern "C" void kernel_launch(void* const* d_in, const int* in_sizes, int n_in,
                              void* d_out, int out_size, void* d_ws, size_t ws_size,
                              hipStream_t stream) {
  const float* x  = (const float*)d_in[0];
  const int*   lb = (const int*)d_in[1];
  const float* W  = (const float*)d_in[2];
  const float* b  = (const float*)d_in[3];
  float* out = (float*)d_out;

  char* ws = (char*)d_ws;
  const size_t OFF_W   = (size_t)XELEMS;          // 2097152
  const size_t OFF_SP  = OFF_W + WBYTES;          // 53346304
  const size_t OFF_TGT = OFF_SP + (size_t)N_ROWS * SPLITS * 4;
  char*  xb    = ws;
  char*  wb    = ws + OFF_W;
  float* spart = (float*)(ws + OFF_SP);
  float* tgt   = (float*)(ws + OFF_TGT);

  cvt_kernel<<<13024, 256, 0, stream>>>(x, W, ws);
  tgt_kernel<<<1024, 256, 0, stream>>>(x, lb, W, b, tgt);
  lse_kernel<<<1024, 256, 0, stream>>>(xb, wb, b, spart);
  combine_kernel<<<1, 256, 0, stream>>>(spart, tgt, out);
}